// Round 12
// baseline (47.234 us; speedup 1.0000x reference)
//
#include <hip/hip_runtime.h>
#include <math.h>

#define NDET 16
#define NDIM 16

// ---- quad (4-lane) DPP broadcast: pure VALU, no LDS path -----------------
template<int OWNER>
__device__ __forceinline__ float bcast4f(float v) {
    constexpr int ctrl = OWNER * 0x55;  // quad_perm:[OWNER]*4
    return __int_as_float(
        __builtin_amdgcn_mov_dpp(__float_as_int(v), ctrl, 0xF, 0xF, true));
}

// ---- Householder QR step, COLUMN-INVOLUTION ORDER (R11-verbatim) ----------
// Step K eliminates global column perm(K) = ((K&3)<<2)|(K>>2): involution,
// 6 transpositions -> det(P)=+1. Owner lane = K&3, local col = K>>2, and
// local cols j < K>>2 are retired on EVERY lane -> uniform shrinking j-loop.
template<int K>
__device__ __forceinline__ void qr_step(float (&c)[4][16], float &prod, float &sgn) {
    constexpr int OWNER = K & 3;
    constexpr int LC    = K >> 2;
    constexpr int JMIN  = K >> 2;

    float s0 = 0.0f, s1 = 0.0f;
    #pragma unroll
    for (int i = K; i < 16; i += 2)     s0 = fmaf(c[LC][i], c[LC][i], s0);
    #pragma unroll
    for (int i = K + 1; i < 16; i += 2) s1 = fmaf(c[LC][i], c[LC][i], s1);

    const float n2    = bcast4f<OWNER>(s0 + s1);
    const float xK    = bcast4f<OWNER>(c[LC][K]);
    const float alpha = __builtin_amdgcn_sqrtf(n2);          // ||x|| > 0 a.s.
    const float vK    = xK + copysignf(alpha, xK);           // |vK| = alpha + |xK|
    const float beta  = __builtin_amdgcn_rcpf(alpha * fabsf(vK));
    prod *= alpha;
    sgn = (xK < 0.0f) ? -sgn : sgn;

    float bv[16];                       // const-indexed -> registers
    bv[K] = vK;
    #pragma unroll
    for (int i = K + 1; i < 16; ++i) bv[i] = bcast4f<OWNER>(c[LC][i]);

    #pragma unroll
    for (int j = JMIN; j < 4; ++j) {
        float w0 = bv[K] * c[j][K], w1 = 0.0f;
        #pragma unroll
        for (int i = K + 1; i < 16; i += 2) w0 = fmaf(bv[i], c[j][i], w0);
        #pragma unroll
        for (int i = K + 2; i < 16; i += 2) w1 = fmaf(bv[i], c[j][i], w1);
        const float t = (w0 + w1) * beta;
        #pragma unroll
        for (int i = K; i < 16; ++i)
            c[j][i] = fmaf(-t, bv[i], c[j][i]);
    }
}

// Step-level dual-stream interleave: A and B reflections alternate, giving
// the scheduler 2x independent work inside every serial chain. (R6 tried
// whole-factorization granularity and the compiler serialized; moving B's
// step K past A's steps K+1..14 would cross 14 dependent reflections.)
template<int K>
__device__ __forceinline__ void qr_dual(float (&cA)[4][16], float (&cB)[4][16],
                                        float &pA, float &pB,
                                        float &sA, float &sB) {
    qr_step<K>(cA, pA, sA);
    qr_step<K>(cB, pB, sB);
    if constexpr (K < 14) qr_dual<K + 1>(cA, cB, pA, pB, sA, sB);
}

__global__ __launch_bounds__(256) void logabssumdet_kernel(
    const float* __restrict__ a,
    const float* __restrict__ b,
    const float* __restrict__ w,
    float* __restrict__ out,
    int n_samples)
{
    const int tid    = threadIdx.x;
    const int lane4  = tid & 3;
    const int group  = tid >> 2;                    // 0..63 in block
    const int mat_id = blockIdx.x * 64 + group;     // = sample*16 + det
    const int n_mats = n_samples * NDET;

    __shared__ float sx[64];
    __shared__ float ss[64];

    float x = 0.0f, sgn = 1.0f;

    if (mat_id < n_mats) {
        const float4* mbA =
            reinterpret_cast<const float4*>(a + (size_t)mat_id * (NDIM * NDIM)) + lane4;
        const float4* mbB =
            reinterpret_cast<const float4*>(b + (size_t)mat_id * (NDIM * NDIM)) + lane4;

        float cA[4][16], cB[4][16];
        #pragma unroll
        for (int i = 0; i < 16; ++i) {              // all 32 loads issued up front
            const float4 vA = mbA[i * 4];
            const float4 vB = mbB[i * 4];
            cA[0][i] = vA.x; cA[1][i] = vA.y; cA[2][i] = vA.z; cA[3][i] = vA.w;
            cB[0][i] = vB.x; cB[1][i] = vB.y; cB[2][i] = vB.z; cB[3][i] = vB.w;
        }

        float pA = 1.0f, pB = 1.0f;                 // products of alpha_K (>0)
        float sA = 1.0f, sB = 1.0f;                 // products of s_K
        qr_dual<0>(cA, cB, pA, pB, sA, sB);         // 15 reflections each
        // remaining column perm(15)=15: lane 3, local 3, row 15
        pA *= bcast4f<3>(cA[3][15]);
        pB *= bcast4f<3>(cB[3][15]);

        x = __logf(fabsf(pA)) + __logf(fabsf(pB));  // f32-range safe (R11-proven)
        sgn = sA * sB;
        sgn = (pA < 0.0f) ? -sgn : sgn;
        sgn = (pB < 0.0f) ? -sgn : sgn;
    }

    if (lane4 == 0) { sx[group] = x; ss[group] = sgn; }
    __syncthreads();

    // 4 samples per block; one thread finishes each sample's 16-det LSE
    if (tid < 4) {
        const int sample = blockIdx.x * 4 + tid;
        if (sample < n_samples) {
            const int base = tid * NDET;
            float xmax = -INFINITY;
            #pragma unroll
            for (int d = 0; d < NDET; ++d) xmax = fmaxf(xmax, sx[base + d]);
            float sum = 0.0f;
            #pragma unroll
            for (int d = 0; d < NDET; ++d)
                sum += ss[base + d] * __expf(sx[base + d] - xmax) * w[d];
            out[sample] = __logf(fabsf(sum)) + xmax;
            out[n_samples + sample] = (sum > 0.0f) ? 1.0f : ((sum < 0.0f) ? -1.0f : 0.0f);
        }
    }
}

extern "C" void kernel_launch(void* const* d_in, const int* in_sizes, int n_in,
                              void* d_out, int out_size, void* d_ws, size_t ws_size,
                              hipStream_t stream)
{
    const float* a = (const float*)d_in[0];
    const float* b = (const float*)d_in[1];
    const float* w = (const float*)d_in[2];
    float* out = (float*)d_out;

    const int n_samples = in_sizes[0] / (NDET * NDIM * NDIM);
    const int blocks = (n_samples + 3) / 4;   // 4 samples (64 dets) per block
    logabssumdet_kernel<<<blocks, 256, 0, stream>>>(a, b, w, out, n_samples);
}